// Round 1
// baseline (288.211 us; speedup 1.0000x reference)
//
#include <hip/hip_runtime.h>
#include <hip/hip_bf16.h>

// Problem constants
#define BB     8
#define HH     16
#define QLEN   256
#define DH     128
#define BSZ    16
#define MAXB   256
#define KT     64            // kv tile
#define BHQ    (BB*HH*QLEN)  // 32768 rows

typedef __attribute__((ext_vector_type(8))) short bf16x8;
typedef __attribute__((ext_vector_type(4))) float f32x4;

__device__ __forceinline__ unsigned short f2bf(float f) {
  union { float f; unsigned u; } c; c.f = f;
  unsigned r = (c.u + 0x7fffu + ((c.u >> 16) & 1u)) >> 16;  // RNE truncate
  return (unsigned short)r;
}

// One block = (b, h, kv-chunk). 8 waves x 32 q-rows = all 256 q rows.
// K LDS: row-major [64][128] bf16, XOR swizzle ((row&7)<<4).
// V LDS: transposed [128][64] bf16, XOR swizzle (((d^(d>>3))&7)<<4).
// P LDS: per-wave [32][64] bf16, XOR swizzle ((row&7)<<4)  (D-layout -> A-layout).
__launch_bounds__(512, 2)
__global__ void paged_attn_kernel(const float* __restrict__ qg,
                                  const float* __restrict__ kc,
                                  const float* __restrict__ vc,
                                  const int* __restrict__ bt,
                                  const int* __restrict__ sl,
                                  float* __restrict__ opart,   // [nkv][BHQ][DH] (or out if nkv==1)
                                  float* __restrict__ mpart,   // [nkv][BHQ]
                                  float* __restrict__ lpart,   // [nkv][BHQ]
                                  int nkv) {
  __shared__ unsigned short kls[KT * DH];     // 16 KiB
  __shared__ unsigned short vls[DH * KT];     // 16 KiB
  __shared__ unsigned short pls[8][32 * KT];  // 32 KiB

  const int tid  = threadIdx.x;
  const int wave = tid >> 6;
  const int lane = tid & 63;
  const int lg   = lane >> 4;   // 16-lane group 0..3
  const int ll   = lane & 15;

  const int c  = blockIdx.x % nkv;
  const int bh = blockIdx.x / nkv;
  const int b  = bh >> 4;       // H = 16
  const int h  = bh & 15;

  const int seq = sl[b];
  const int nt  = (seq + KT - 1) / KT;
  const int per = (nt + nkv - 1) / nkv;
  const int t0  = c * per;
  const int t1  = (t0 + per < nt) ? (t0 + per) : nt;

  // ---- Q fragments, scale*log2(e) folded in ----
  const float qscale = 0.08838834764831845f * 1.4426950408889634f;
  bf16x8 qf[2][4];
  {
    const float* qb = qg + ((size_t)bh * QLEN + wave * 32) * DH;
#pragma unroll
    for (int mi = 0; mi < 2; ++mi) {
      const float* qr = qb + (mi * 16 + ll) * DH;
#pragma unroll
      for (int ks = 0; ks < 4; ++ks) {
        const float4 a  = *(const float4*)(qr + ks * 32 + lg * 8);
        const float4 bv = *(const float4*)(qr + ks * 32 + lg * 8 + 4);
        bf16x8 v;
        v[0] = (short)f2bf(a.x * qscale);  v[1] = (short)f2bf(a.y * qscale);
        v[2] = (short)f2bf(a.z * qscale);  v[3] = (short)f2bf(a.w * qscale);
        v[4] = (short)f2bf(bv.x * qscale); v[5] = (short)f2bf(bv.y * qscale);
        v[6] = (short)f2bf(bv.z * qscale); v[7] = (short)f2bf(bv.w * qscale);
        qf[mi][ks] = v;
      }
    }
  }

  f32x4 acc[2][8];
#pragma unroll
  for (int mi = 0; mi < 2; ++mi)
#pragma unroll
    for (int nj = 0; nj < 8; ++nj)
      acc[mi][nj] = (f32x4){0.f, 0.f, 0.f, 0.f};
  float mrow[2][4], lrow[2][4];
#pragma unroll
  for (int mi = 0; mi < 2; ++mi)
#pragma unroll
    for (int r = 0; r < 4; ++r) { mrow[mi][r] = -1e30f; lrow[mi][r] = 0.f; }

  for (int t = t0; t < t1; ++t) {
    const int kv0 = t * KT;
    __syncthreads();  // previous tile's LDS readers done
    // ---- stage K + V^T (fp32 -> bf16), 2048 float4 each / 512 threads ----
#pragma unroll
    for (int i = 0; i < 4; ++i) {
      const int f    = i * 512 + tid;
      const int row  = f >> 5;        // kv within tile
      const int col4 = f & 31;        // float4 index along d
      const int kv   = kv0 + row;
      const int phys = bt[b * MAXB + (kv >> 4)];
      const size_t gb = (((size_t)phys * HH + h) * BSZ + (kv & 15)) * DH + col4 * 4;
      const float4 kk = *(const float4*)(kc + gb);
      const float4 vv = *(const float4*)(vc + gb);
      const unsigned lo = (unsigned)f2bf(kk.x) | ((unsigned)f2bf(kk.y) << 16);
      const unsigned hi = (unsigned)f2bf(kk.z) | ((unsigned)f2bf(kk.w) << 16);
      const int kb = (row * 256 + col4 * 8) ^ ((row & 7) << 4);
      *(uint2*)((char*)kls + kb) = make_uint2(lo, hi);
      const float vvv[4] = {vv.x, vv.y, vv.z, vv.w};
#pragma unroll
      for (int jj = 0; jj < 4; ++jj) {
        const int d  = col4 * 4 + jj;
        const int sw = ((d ^ (d >> 3)) & 7) << 4;
        const int vb = (d * 128 + row * 2) ^ sw;
        *(unsigned short*)((char*)vls + vb) = f2bf(vvv[jj]);
      }
    }
    __syncthreads();

    // ---- S = Q K^T ----
    f32x4 s[2][4];
#pragma unroll
    for (int mi = 0; mi < 2; ++mi)
#pragma unroll
      for (int ni = 0; ni < 4; ++ni)
        s[mi][ni] = (f32x4){0.f, 0.f, 0.f, 0.f};
#pragma unroll
    for (int ni = 0; ni < 4; ++ni) {
      bf16x8 kf[4];
      const int krow = ni * 16 + ll;
#pragma unroll
      for (int ks = 0; ks < 4; ++ks) {
        const int byte = (krow * 256 + (ks * 32 + lg * 8) * 2) ^ ((krow & 7) << 4);
        kf[ks] = *(const bf16x8*)((const char*)kls + byte);
      }
#pragma unroll
      for (int ks = 0; ks < 4; ++ks)
#pragma unroll
        for (int mi = 0; mi < 2; ++mi)
          s[mi][ni] = __builtin_amdgcn_mfma_f32_16x16x32_bf16(qf[mi][ks], kf[ks], s[mi][ni], 0, 0, 0);
    }

    // ---- online softmax (wave-parallel over 16-lane row groups), write P ----
#pragma unroll
    for (int mi = 0; mi < 2; ++mi) {
#pragma unroll
      for (int r = 0; r < 4; ++r) {
#pragma unroll
        for (int ni = 0; ni < 4; ++ni) {
          const int col = kv0 + ni * 16 + ll;
          if (col >= seq) s[mi][ni][r] = -1e30f;
        }
        float v = fmaxf(fmaxf(s[mi][0][r], s[mi][1][r]), fmaxf(s[mi][2][r], s[mi][3][r]));
        v = fmaxf(v, __shfl_xor(v, 1));
        v = fmaxf(v, __shfl_xor(v, 2));
        v = fmaxf(v, __shfl_xor(v, 4));
        v = fmaxf(v, __shfl_xor(v, 8));
        const float mnew  = fmaxf(mrow[mi][r], v);
        const float alpha = exp2f(mrow[mi][r] - mnew);
        mrow[mi][r] = mnew;
        float rs = 0.f;
        const int prow = mi * 16 + lg * 4 + r;
        const int pswz = (prow & 7) << 4;
#pragma unroll
        for (int ni = 0; ni < 4; ++ni) {
          const float p = exp2f(s[mi][ni][r] - mnew);
          rs += p;
          const int pb = (prow * 128 + (ni * 16 + ll) * 2) ^ pswz;
          *(unsigned short*)((char*)pls[wave] + pb) = f2bf(p);
        }
        rs += __shfl_xor(rs, 1);
        rs += __shfl_xor(rs, 2);
        rs += __shfl_xor(rs, 4);
        rs += __shfl_xor(rs, 8);
        lrow[mi][r] = lrow[mi][r] * alpha + rs;
#pragma unroll
        for (int nj = 0; nj < 8; ++nj)
          acc[mi][nj][r] *= alpha;
      }
    }

    asm volatile("s_waitcnt lgkmcnt(0)" ::: "memory");  // P writes visible to own-wave reads

    // ---- O += P V ----
    bf16x8 pa[2][2];
#pragma unroll
    for (int mi = 0; mi < 2; ++mi)
#pragma unroll
      for (int k2 = 0; k2 < 2; ++k2) {
        const int prow = mi * 16 + ll;
        const int byte = (prow * 128 + (k2 * 32 + lg * 8) * 2) ^ ((prow & 7) << 4);
        pa[mi][k2] = *(const bf16x8*)((const char*)pls[wave] + byte);
      }
#pragma unroll
    for (int k2 = 0; k2 < 2; ++k2)
#pragma unroll
      for (int nj = 0; nj < 8; ++nj) {
        const int d    = nj * 16 + ll;
        const int sw   = ((d ^ (d >> 3)) & 7) << 4;
        const int byte = (d * 128 + (k2 * 32 + lg * 8) * 2) ^ sw;
        const bf16x8 vbf = *(const bf16x8*)((const char*)vls + byte);
#pragma unroll
        for (int mi = 0; mi < 2; ++mi)
          acc[mi][nj] = __builtin_amdgcn_mfma_f32_16x16x32_bf16(pa[mi][k2], vbf, acc[mi][nj], 0, 0, 0);
      }
  }

  // ---- epilogue ----
  if (nkv == 1) {
#pragma unroll
    for (int mi = 0; mi < 2; ++mi)
#pragma unroll
      for (int r = 0; r < 4; ++r) {
        const float inv = 1.0f / lrow[mi][r];
        const int grow  = bh * QLEN + wave * 32 + mi * 16 + lg * 4 + r;
        float* orow = opart + (size_t)grow * DH;
#pragma unroll
        for (int nj = 0; nj < 8; ++nj)
          orow[nj * 16 + ll] = acc[mi][nj][r] * inv;
      }
  } else {
#pragma unroll
    for (int mi = 0; mi < 2; ++mi)
#pragma unroll
      for (int r = 0; r < 4; ++r) {
        const int grow = bh * QLEN + wave * 32 + mi * 16 + lg * 4 + r;
        float* orow = opart + ((size_t)c * BHQ + grow) * DH;
#pragma unroll
        for (int nj = 0; nj < 8; ++nj)
          orow[nj * 16 + ll] = acc[mi][nj][r];   // unnormalized
        if (ll == 0) {
          mpart[c * BHQ + grow] = mrow[mi][r];
          lpart[c * BHQ + grow] = lrow[mi][r];
        }
      }
  }
}

__global__ void combine_kernel(const float* __restrict__ op,
                               const float* __restrict__ mp,
                               const float* __restrict__ lp,
                               float* __restrict__ out, int nkv) {
  const int idx = blockIdx.x * 256 + threadIdx.x;  // float4 index over BHQ*DH/4
  const int row = idx >> 5;                        // 32 float4 per row
  float M = -1e30f;
  for (int cc = 0; cc < nkv; ++cc) M = fmaxf(M, mp[cc * BHQ + row]);
  float den = 0.f;
  float4 o = make_float4(0.f, 0.f, 0.f, 0.f);
  for (int cc = 0; cc < nkv; ++cc) {
    const float w = exp2f(mp[cc * BHQ + row] - M);
    den += lp[cc * BHQ + row] * w;
    const float4 v = ((const float4*)op)[(size_t)cc * (BHQ * (DH / 4)) + idx];
    o.x += w * v.x; o.y += w * v.y; o.z += w * v.z; o.w += w * v.w;
  }
  const float inv = 1.0f / den;
  ((float4*)out)[idx] = make_float4(o.x * inv, o.y * inv, o.z * inv, o.w * inv);
}

extern "C" void kernel_launch(void* const* d_in, const int* in_sizes, int n_in,
                              void* d_out, int out_size, void* d_ws, size_t ws_size,
                              hipStream_t stream) {
  const float* q  = (const float*)d_in[0];
  const float* kc = (const float*)d_in[1];
  const float* vc = (const float*)d_in[2];
  const int* bt   = (const int*)d_in[3];
  const int* sl   = (const int*)d_in[4];
  float* out = (float*)d_out;

  const size_t perchunk = (size_t)BHQ * DH * sizeof(float) + (size_t)BHQ * 2 * sizeof(float);
  int nkv = 1;
  if (ws_size >= 4 * perchunk) nkv = 4;
  else if (ws_size >= 2 * perchunk) nkv = 2;

  float* op = (nkv == 1) ? out : (float*)d_ws;
  float* mp = (float*)d_ws + (size_t)nkv * BHQ * DH;
  float* lp = mp + (size_t)nkv * BHQ;

  paged_attn_kernel<<<dim3(BB * HH * nkv), dim3(512), 0, stream>>>(q, kc, vc, bt, sl, op, mp, lp, nkv);
  if (nkv > 1)
    combine_kernel<<<dim3(BHQ * DH / 4 / 256), dim3(256), 0, stream>>>(op, mp, lp, out, nkv);
}